// Round 5
// baseline (158.922 us; speedup 1.0000x reference)
//
#include <hip/hip_runtime.h>

typedef unsigned short u16;
typedef unsigned int u32;
typedef __attribute__((ext_vector_type(8))) short short8;   // bf16x8 MFMA frag
typedef __attribute__((ext_vector_type(4))) float f32x4;    // MFMA acc frag

// Problem constants (match reference)
constexpr int NODES = 100000;
constexpr int EDGES = 800000;
constexpr int DIM = 128;       // node dim
constexpr int EDIM = 8;        // edge attr dim
constexpr int HEADS = 8;

// counting-sort scan geometry
constexpr int SCAN_BLK = 512;
constexpr int NSCAN_BLKS = (NODES + SCAN_BLK - 1) / SCAN_BLK;  // 196
constexpr int NPAD = NSCAN_BLKS * SCAN_BLK;                    // 100352

// scatter_gate work split: 4 edges per thread
constexpr int SG_THREADS = EDGES / 4;                          // 200000

__device__ inline u16 f2bf(float f) {              // f32 -> bf16 RNE
    u32 u = __float_as_uint(f);
    u = (u + 0x7FFFu + ((u >> 16) & 1u)) >> 16;
    return (u16)u;
}
__device__ inline float bf2f(u16 s) {              // bf16 -> f32 exact
    return __uint_as_float(((u32)s) << 16);
}
__device__ inline u32 packbf(float a, float b) {
    return (u32)f2bf(a) | ((u32)f2bf(b) << 16);
}

// ---------------------------------------------------------------------------
// Convert W_node (128x128 f32, row-major W[n][k]) to bf16. No transpose: the
// MFMA B-fragment wants B[k][n] = W[n][k], i.e. contiguous k within a row.
// ---------------------------------------------------------------------------
__global__ __launch_bounds__(256) void convert_w(const float* __restrict__ W,
                                                 u16* __restrict__ Wb) {
    int i = blockIdx.x * 256 + threadIdx.x;   // 64 blocks
    Wb[i] = f2bf(W[i]);
}

// ---------------------------------------------------------------------------
// node_proj via MFMA (proven in R4): xp_bf16 = bf16(x @ W.T + b).
// ---------------------------------------------------------------------------
__global__ __launch_bounds__(256) void node_proj_mfma(const float* __restrict__ x,
                                                      const u16* __restrict__ Wb,
                                                      const float* __restrict__ bn,
                                                      u16* __restrict__ xpb) {
    __shared__ u16 sW[128 * 136];   // 34816 B, +8 pad per row

    const int tid = threadIdx.x;
    {   // stage W: 128 rows x 16 chunks of 8 bf16 (16B)
        const short8* g = reinterpret_cast<const short8*>(Wb);
        #pragma unroll
        for (int i = tid; i < 128 * 16; i += 256) {
            int row = i >> 4, ch = i & 15;
            *reinterpret_cast<short8*>(&sW[row * 136 + ch * 8]) = g[row * 16 + ch];
        }
    }
    __syncthreads();

    const int w = tid >> 6;        // wave 0..3
    const int l = tid & 63;
    const int lr = l & 15;
    const int lh = l >> 4;
    const int m0 = blockIdx.x * 128 + w * 32;

    f32x4 acc[2][8];
    #pragma unroll
    for (int mt = 0; mt < 2; ++mt)
        #pragma unroll
        for (int nt = 0; nt < 8; ++nt) acc[mt][nt] = f32x4{0, 0, 0, 0};

    #pragma unroll
    for (int kk = 0; kk < 4; ++kk) {
        const int kb = kk * 32 + lh * 8;
        short8 a0, a1;
        {
            int row = m0 + lr;  row = row < NODES ? row : 0;
            const float* p = x + (size_t)row * DIM + kb;
            float4 f0 = *reinterpret_cast<const float4*>(p);
            float4 f1 = *reinterpret_cast<const float4*>(p + 4);
            a0[0]=f2bf(f0.x); a0[1]=f2bf(f0.y); a0[2]=f2bf(f0.z); a0[3]=f2bf(f0.w);
            a0[4]=f2bf(f1.x); a0[5]=f2bf(f1.y); a0[6]=f2bf(f1.z); a0[7]=f2bf(f1.w);
        }
        {
            int row = m0 + 16 + lr;  row = row < NODES ? row : 0;
            const float* p = x + (size_t)row * DIM + kb;
            float4 f0 = *reinterpret_cast<const float4*>(p);
            float4 f1 = *reinterpret_cast<const float4*>(p + 4);
            a1[0]=f2bf(f0.x); a1[1]=f2bf(f0.y); a1[2]=f2bf(f0.z); a1[3]=f2bf(f0.w);
            a1[4]=f2bf(f1.x); a1[5]=f2bf(f1.y); a1[6]=f2bf(f1.z); a1[7]=f2bf(f1.w);
        }
        #pragma unroll
        for (int nt = 0; nt < 8; ++nt) {
            short8 b = *reinterpret_cast<const short8*>(&sW[(nt * 16 + lr) * 136 + kb]);
            acc[0][nt] = __builtin_amdgcn_mfma_f32_16x16x32_bf16(a0, b, acc[0][nt], 0, 0, 0);
            acc[1][nt] = __builtin_amdgcn_mfma_f32_16x16x32_bf16(a1, b, acc[1][nt], 0, 0, 0);
        }
    }

    float bias[8];
    #pragma unroll
    for (int nt = 0; nt < 8; ++nt) bias[nt] = bn[nt * 16 + lr];

    #pragma unroll
    for (int mt = 0; mt < 2; ++mt) {
        #pragma unroll
        for (int r = 0; r < 4; ++r) {
            int grow = m0 + mt * 16 + lh * 4 + r;
            if (grow < NODES) {
                #pragma unroll
                for (int nt = 0; nt < 8; ++nt)
                    xpb[(size_t)grow * DIM + nt * 16 + lr] =
                        f2bf(acc[mt][nt][r] + bias[nt]);
            }
        }
    }
}

// ---------------------------------------------------------------------------
// Counting sort of edges by target node (proven)
// ---------------------------------------------------------------------------
__global__ __launch_bounds__(256) void hist_kernel(const int* __restrict__ ei,
                                                   int* __restrict__ cnt) {
    int e = blockIdx.x * 256 + threadIdx.x;
    if (e < EDGES) atomicAdd(&cnt[ei[EDGES + e]], 1);
}

__global__ __launch_bounds__(256) void scan_block_sums(const int* __restrict__ cnt,
                                                       int* __restrict__ partial) {
    __shared__ int sd[256];
    int b = blockIdx.x, t = threadIdx.x;
    int s = cnt[b * SCAN_BLK + t] + cnt[b * SCAN_BLK + 256 + t];
    sd[t] = s; __syncthreads();
    for (int d = 128; d > 0; d >>= 1) {
        if (t < d) sd[t] += sd[t + d];
        __syncthreads();
    }
    if (t == 0) partial[b] = sd[0];
}

__global__ __launch_bounds__(256) void scan_partials(int* __restrict__ partial) {
    __shared__ int sd[256];
    int t = threadIdx.x;
    int v = (t < NSCAN_BLKS) ? partial[t] : 0;
    sd[t] = v; __syncthreads();
    for (int d = 1; d < 256; d <<= 1) {
        int u = (t >= d) ? sd[t - d] : 0;
        __syncthreads();
        sd[t] += u;
        __syncthreads();
    }
    if (t < NSCAN_BLKS) partial[t] = sd[t] - v;   // exclusive
}

__global__ __launch_bounds__(256) void scan_write(const int* __restrict__ cnt,
                                                  const int* __restrict__ partial,
                                                  int* __restrict__ start) {
    __shared__ int sd[256];
    int b = blockIdx.x, t = threadIdx.x;
    int i0 = b * SCAN_BLK + 2 * t;
    int c0 = cnt[i0], c1 = cnt[i0 + 1];
    int s = c0 + c1;
    sd[t] = s; __syncthreads();
    for (int d = 1; d < 256; d <<= 1) {
        int u = (t >= d) ? sd[t - d] : 0;
        __syncthreads();
        sd[t] += u;
        __syncthreads();
    }
    int excl = sd[t] - s + partial[b];
    start[i0] = excl;
    start[i0 + 1] = excl + c0;
}

// ---------------------------------------------------------------------------
// Scatter + gate precompute v2: 4 edges/thread (independent atomic->store
// chains). Unified 32B record at sorted position p:
//   bytes [0,16): 8 gates bf16   [16,20): src   [20,32): pad
// One random 32B region per edge (one line touch) vs two streams before.
// ---------------------------------------------------------------------------
__global__ __launch_bounds__(256) void scatter_gate(const int* __restrict__ ei,
                                                    const float* __restrict__ ea,
                                                    const float* __restrict__ We,
                                                    const float* __restrict__ be,
                                                    int* __restrict__ start,
                                                    char* __restrict__ recA) {
    __shared__ float sW[HEADS * EDIM];
    __shared__ float sb[HEADS];
    if (threadIdx.x < HEADS * EDIM) sW[threadIdx.x] = We[threadIdx.x];
    if (threadIdx.x < HEADS) sb[threadIdx.x] = be[threadIdx.x];
    __syncthreads();

    const int t0 = blockIdx.x * 256 + threadIdx.x;
    if (t0 >= SG_THREADS) return;

    int e[4], src[4], tgt[4], p[4];
    float4 a0[4], a1[4];

    #pragma unroll
    for (int k = 0; k < 4; ++k) {
        e[k] = t0 + k * SG_THREADS;
        src[k] = ei[e[k]];
        tgt[k] = ei[EDGES + e[k]];
        a0[k] = *reinterpret_cast<const float4*>(ea + (size_t)e[k] * EDIM);
        a1[k] = *reinterpret_cast<const float4*>(ea + (size_t)e[k] * EDIM + 4);
    }
    #pragma unroll
    for (int k = 0; k < 4; ++k) p[k] = atomicAdd(&start[tgt[k]], 1);

    #pragma unroll
    for (int k = 0; k < 4; ++k) {
        float g[HEADS];
        #pragma unroll
        for (int h = 0; h < HEADS; ++h) {
            const float* w = &sW[h * EDIM];
            float z = sb[h]
                    + a0[k].x * w[0] + a0[k].y * w[1] + a0[k].z * w[2] + a0[k].w * w[3]
                    + a1[k].x * w[4] + a1[k].y * w[5] + a1[k].z * w[6] + a1[k].w * w[7];
            g[h] = 1.0f / (1.0f + __expf(-z));
        }
        uint4 gw;
        gw.x = packbf(g[0], g[1]);
        gw.y = packbf(g[2], g[3]);
        gw.z = packbf(g[4], g[5]);
        gw.w = packbf(g[6], g[7]);
        char* r = recA + (size_t)p[k] * 32;
        *reinterpret_cast<uint4*>(r) = gw;
        *reinterpret_cast<int*>(r + 16) = src[k];
    }
}

// ---------------------------------------------------------------------------
// Aggregate v3: 32-lane group per node; rec stream sequential (128B / 4
// edges), one random hop (xpb gather). Lane's gate = 2B broadcast load.
// ---------------------------------------------------------------------------
__global__ __launch_bounds__(256) void aggregate_v3(const u16* __restrict__ xpb,
                                                    const int* __restrict__ startM,
                                                    const char* __restrict__ recA,
                                                    float* __restrict__ out) {
    const int n = blockIdx.x * 8 + (threadIdx.x >> 5);
    if (n >= NODES) return;
    const int l = threadIdx.x & 31;
    const int h = l >> 2;

    int j = (n == 0) ? 0 : startM[n - 1];
    const int jend = startM[n];

    float4 acc = {0, 0, 0, 0};

    for (; j + 4 <= jend; j += 4) {
        const char* r0 = recA + (size_t)(j + 0) * 32;
        const char* r1 = recA + (size_t)(j + 1) * 32;
        const char* r2 = recA + (size_t)(j + 2) * 32;
        const char* r3 = recA + (size_t)(j + 3) * 32;
        int s0 = *reinterpret_cast<const int*>(r0 + 16);
        int s1 = *reinterpret_cast<const int*>(r1 + 16);
        int s2 = *reinterpret_cast<const int*>(r2 + 16);
        int s3 = *reinterpret_cast<const int*>(r3 + 16);
        float g0 = bf2f(reinterpret_cast<const u16*>(r0)[h]);
        float g1 = bf2f(reinterpret_cast<const u16*>(r1)[h]);
        float g2 = bf2f(reinterpret_cast<const u16*>(r2)[h]);
        float g3 = bf2f(reinterpret_cast<const u16*>(r3)[h]);
        ushort4 u0 = *reinterpret_cast<const ushort4*>(xpb + (size_t)s0 * DIM + l * 4);
        ushort4 u1 = *reinterpret_cast<const ushort4*>(xpb + (size_t)s1 * DIM + l * 4);
        ushort4 u2 = *reinterpret_cast<const ushort4*>(xpb + (size_t)s2 * DIM + l * 4);
        ushort4 u3 = *reinterpret_cast<const ushort4*>(xpb + (size_t)s3 * DIM + l * 4);
        acc.x += g0 * bf2f(u0.x); acc.y += g0 * bf2f(u0.y);
        acc.z += g0 * bf2f(u0.z); acc.w += g0 * bf2f(u0.w);
        acc.x += g1 * bf2f(u1.x); acc.y += g1 * bf2f(u1.y);
        acc.z += g1 * bf2f(u1.z); acc.w += g1 * bf2f(u1.w);
        acc.x += g2 * bf2f(u2.x); acc.y += g2 * bf2f(u2.y);
        acc.z += g2 * bf2f(u2.z); acc.w += g2 * bf2f(u2.w);
        acc.x += g3 * bf2f(u3.x); acc.y += g3 * bf2f(u3.y);
        acc.z += g3 * bf2f(u3.z); acc.w += g3 * bf2f(u3.w);
    }
    for (; j < jend; ++j) {
        const char* r0 = recA + (size_t)j * 32;
        int s0 = *reinterpret_cast<const int*>(r0 + 16);
        float g0 = bf2f(reinterpret_cast<const u16*>(r0)[h]);
        ushort4 u0 = *reinterpret_cast<const ushort4*>(xpb + (size_t)s0 * DIM + l * 4);
        acc.x += g0 * bf2f(u0.x); acc.y += g0 * bf2f(u0.y);
        acc.z += g0 * bf2f(u0.z); acc.w += g0 * bf2f(u0.w);
    }

    reinterpret_cast<float4*>(out)[(size_t)n * 32 + l] = acc;
}

// ---------------------------------------------------------------------------
// Fallback (small ws): per-edge atomic scatter reading bf16 xp
// ---------------------------------------------------------------------------
__global__ __launch_bounds__(256) void edge_scatter(const int* __restrict__ ei,
                                                    const float* __restrict__ ea,
                                                    const float* __restrict__ We,
                                                    const float* __restrict__ be,
                                                    const u16* __restrict__ xpb,
                                                    float* __restrict__ out) {
    __shared__ float sW[HEADS * EDIM];
    __shared__ float sb[HEADS];
    if (threadIdx.x < HEADS * EDIM) sW[threadIdx.x] = We[threadIdx.x];
    if (threadIdx.x < HEADS) sb[threadIdx.x] = be[threadIdx.x];
    __syncthreads();

    const int t = blockIdx.x * 256 + threadIdx.x;
    const int e = t >> 5;
    const int l = t & 31;
    if (e >= EDGES) return;

    const int src = ei[e];
    const int tgt = ei[EDGES + e];
    const int h = l >> 2;

    float4 ea0 = *reinterpret_cast<const float4*>(ea + (size_t)e * EDIM);
    float4 ea1 = *reinterpret_cast<const float4*>(ea + (size_t)e * EDIM + 4);
    float4 wa = *reinterpret_cast<const float4*>(&sW[h * EDIM]);
    float4 wb = *reinterpret_cast<const float4*>(&sW[h * EDIM + 4]);
    float z = sb[h]
            + ea0.x * wa.x + ea0.y * wa.y + ea0.z * wa.z + ea0.w * wa.w
            + ea1.x * wb.x + ea1.y * wb.y + ea1.z * wb.z + ea1.w * wb.w;
    float g = 1.0f / (1.0f + __expf(-z));

    ushort4 u = *reinterpret_cast<const ushort4*>(xpb + (size_t)src * DIM + l * 4);
    float* op = out + (size_t)tgt * DIM + l * 4;
    unsafeAtomicAdd(op + 0, bf2f(u.x) * g);
    unsafeAtomicAdd(op + 1, bf2f(u.y) * g);
    unsafeAtomicAdd(op + 2, bf2f(u.z) * g);
    unsafeAtomicAdd(op + 3, bf2f(u.w) * g);
}

// ---------------------------------------------------------------------------
extern "C" void kernel_launch(void* const* d_in, const int* in_sizes, int n_in,
                              void* d_out, int out_size, void* d_ws, size_t ws_size,
                              hipStream_t stream) {
    const float* x   = (const float*)d_in[0];
    const int*   ei  = (const int*)d_in[1];
    const float* eat = (const float*)d_in[2];
    const float* Wn  = (const float*)d_in[3];
    const float* bn  = (const float*)d_in[4];
    const float* We  = (const float*)d_in[5];
    const float* be  = (const float*)d_in[6];
    float* out = (float*)d_out;

    // workspace layout
    u16* Wb  = (u16*)d_ws;                                  // 16384 bf16 (32KB)
    u16* xpb = Wb + DIM * DIM;                              // NODES*128 bf16 (25.6MB)
    int* cnt     = (int*)(xpb + (size_t)NODES * DIM);       // NPAD i32
    int* start   = cnt + NPAD;                              // NPAD i32
    int* partial = start + NPAD;                            // 256 i32
    char* recA   = (char*)(partial + 256);                  // EDGES*32 B (25.6MB)

    const size_t need = (size_t)(DIM * DIM) * 2 + (size_t)NODES * DIM * 2
                      + (size_t)(2 * NPAD + 256) * 4
                      + (size_t)EDGES * 32;                 // ~52.3 MB

    convert_w<<<64, 256, 0, stream>>>(Wn, Wb);
    node_proj_mfma<<<(NODES + 127) / 128, 256, 0, stream>>>(x, Wb, bn, xpb);

    if (ws_size >= need) {
        hipMemsetAsync(cnt, 0, (size_t)NPAD * sizeof(int), stream);
        hist_kernel<<<(EDGES + 255) / 256, 256, 0, stream>>>(ei, cnt);
        scan_block_sums<<<NSCAN_BLKS, 256, 0, stream>>>(cnt, partial);
        scan_partials<<<1, 256, 0, stream>>>(partial);
        scan_write<<<NSCAN_BLKS, 256, 0, stream>>>(cnt, partial, start);
        scatter_gate<<<(SG_THREADS + 255) / 256, 256, 0, stream>>>(ei, eat, We, be,
                                                                   start, recA);
        aggregate_v3<<<(NODES + 7) / 8, 256, 0, stream>>>(xpb, start, recA, out);
    } else {
        hipMemsetAsync(d_out, 0, (size_t)out_size * sizeof(float), stream);
        edge_scatter<<<(EDGES * 32) / 256, 256, 0, stream>>>(ei, eat, We, be, xpb, out);
    }
}